// Round 1
// baseline (142.076 us; speedup 1.0000x reference)
//
#include <hip/hip_runtime.h>

// Problem constants: B=32, S=2048, UNITS=K=512
#define NBATCH 32
#define SEQ    2048
#define NU     512

typedef __attribute__((ext_vector_type(8))) short bf16x8;
typedef __attribute__((ext_vector_type(4))) float f32x4;

__device__ __forceinline__ short bf16_of(float f) {
  union { float f; unsigned u; } v; v.f = f;
  unsigned r = v.u + 0x7fffu + ((v.u >> 16) & 1u);   // RNE
  return (short)(r >> 16);
}

__device__ __forceinline__ float fast_tanh(float x) {
  float ax = __builtin_fabsf(x);
  float t  = __expf(-2.0f * ax);          // v_exp_f32 based, in (0,1]
  float r  = (1.0f - t) / (1.0f + t);     // tanh(|x|), stable for all x
  return x < 0.0f ? -r : r;
}

// ---------- prep 1: Wt_bf16[col][k] = bf16(W[k][col]) ----------
__global__ __launch_bounds__(256) void prep_w(const float* __restrict__ W,
                                              short* __restrict__ Wt) {
  int idx = blockIdx.x * 256 + threadIdx.x;   // 0..262143
  int u = idx >> 9, k = idx & 511;
  Wt[(size_t)u * NU + k] = bf16_of(W[(size_t)k * NU + u]);
}

// ---------- prep 2: first[b][u] = s_prev[b]@U + U_bias + W_bias ----------
__global__ __launch_bounds__(256) void prep_first(const float* __restrict__ sp,
                                                  const float* __restrict__ U,
                                                  const float* __restrict__ Ub,
                                                  const float* __restrict__ Wb,
                                                  float* __restrict__ first) {
  __shared__ float srow[NU];
  int b = blockIdx.x >> 1;        // grid 64: (b, half)
  int half = blockIdx.x & 1;
  int t = threadIdx.x;
  srow[t]       = sp[b * NU + t];
  srow[t + 256] = sp[b * NU + t + 256];
  __syncthreads();
  int col = half * 256 + t;
  float acc = Ub[col] + Wb[col];
  #pragma unroll 8
  for (int k = 0; k < NU; ++k) acc += srow[k] * U[(size_t)k * NU + col];
  first[b * NU + col] = acc;
}

// ---------- main: scores[b*S+s] = sum_u V[u]*tanh(first[b,u] + (h[row]@W)[u]) ----------
__global__ __launch_bounds__(512) void attn_main(
    const float* __restrict__ h,      // (B*S, 512) fp32
    const short* __restrict__ Wt,     // (512 cols, 512 k) bf16 bits
    const float* __restrict__ first,  // (B, 512) incl. U_bias + W_bias
    const float* __restrict__ V,      // (512)
    float* __restrict__ scores)       // (B*S)
{
  __shared__ short wlds[64 * NU];     // 64 KiB: [col][k], XOR-swizzled
  const int tid  = threadIdx.x;
  const int wave = tid >> 6;
  const int lane = tid & 63;
  const int lg   = lane >> 4;         // 0..3
  const int lr   = lane & 15;
  const int row_base = blockIdx.x * 128;
  const int b  = row_base >> 11;      // /2048; 2048 % 128 == 0 -> single b per block
  const int myrow = row_base + wave * 16 + lr;

  // A fragments for all 16 K-steps, held in registers (h read once, coalesced)
  bf16x8 afrag[16];
  const float* hrow = h + (size_t)myrow * NU;
  #pragma unroll
  for (int t = 0; t < 16; ++t) {
    const int k0 = t * 32 + lg * 8;
    float4 x0 = *reinterpret_cast<const float4*>(hrow + k0);
    float4 x1 = *reinterpret_cast<const float4*>(hrow + k0 + 4);
    bf16x8 a;
    a[0] = bf16_of(x0.x); a[1] = bf16_of(x0.y); a[2] = bf16_of(x0.z); a[3] = bf16_of(x0.w);
    a[4] = bf16_of(x1.x); a[5] = bf16_of(x1.y); a[6] = bf16_of(x1.z); a[7] = bf16_of(x1.w);
    afrag[t] = a;
  }

  float spart[4] = {0.f, 0.f, 0.f, 0.f};
  const float* fb = first + b * NU;

  for (int c = 0; c < 8; ++c) {       // 8 N-chunks of 64 cols
    __syncthreads();
    // stage Wt cols [c*64, c*64+64) into LDS [col][k], swizzled
    #pragma unroll
    for (int i = 0; i < 8; ++i) {
      int unit = i * 512 + tid;       // 0..4095 units of 8 shorts
      int col  = unit >> 6;           // 0..63
      int kb   = (unit & 63) << 3;    // 0..511 step 8
      bf16x8 v = *reinterpret_cast<const bf16x8*>(Wt + (size_t)(c * 64 + col) * NU + kb);
      int byte = col * 1024 + ((kb * 2) ^ ((col & 7) << 4));
      *reinterpret_cast<bf16x8*>(reinterpret_cast<char*>(wlds) + byte) = v;
    }
    __syncthreads();

    f32x4 acc[4];
    #pragma unroll
    for (int j = 0; j < 4; ++j) acc[j] = (f32x4){0.f, 0.f, 0.f, 0.f};

    #pragma unroll
    for (int t = 0; t < 16; ++t) {
      const int kbyte = (t * 32 + lg * 8) * 2;
      #pragma unroll
      for (int j = 0; j < 4; ++j) {
        const int col  = j * 16 + lr;
        const int byte = col * 1024 + (kbyte ^ ((col & 7) << 4));
        bf16x8 bfr = *reinterpret_cast<const bf16x8*>(reinterpret_cast<char*>(wlds) + byte);
        acc[j] = __builtin_amdgcn_mfma_f32_16x16x32_bf16(afrag[t], bfr, acc[j], 0, 0, 0);
      }
    }

    // epilogue: tanh + V-weighted accumulation into per-row score partials
    #pragma unroll
    for (int j = 0; j < 4; ++j) {
      const int colg = c * 64 + j * 16 + lr;
      const float fv = fb[colg];
      const float vv = V[colg];
      #pragma unroll
      for (int r = 0; r < 4; ++r)
        spart[r] += vv * fast_tanh(fv + acc[j][r]);
    }
  }

  // reduce over the 16 lanes (cols) within each lane-group
  #pragma unroll
  for (int m = 1; m < 16; m <<= 1) {
    #pragma unroll
    for (int r = 0; r < 4; ++r) spart[r] += __shfl_xor(spart[r], m, 64);
  }
  if (lr == 0) {
    const int r0 = row_base + wave * 16 + lg * 4;  // C rows: (lane>>4)*4 + reg
    #pragma unroll
    for (int r = 0; r < 4; ++r) scores[r0 + r] = spart[r];
  }
}

// ---------- softmax over S per batch (in-place in d_out) + context ----------
__global__ __launch_bounds__(256) void softmax_ctx(const float* __restrict__ sp,
                                                   float* __restrict__ out) {
  const int b = blockIdx.x;
  const int t = threadIdx.x;
  float* w = out + NBATCH * NU + (size_t)b * SEQ;
  __shared__ float red[4];

  float v[8];
  float mx = -1e30f;
  #pragma unroll
  for (int i = 0; i < 8; ++i) { v[i] = w[t + i * 256]; mx = fmaxf(mx, v[i]); }
  #pragma unroll
  for (int m = 1; m < 64; m <<= 1) mx = fmaxf(mx, __shfl_xor(mx, m, 64));
  if ((t & 63) == 0) red[t >> 6] = mx;
  __syncthreads();
  mx = fmaxf(fmaxf(red[0], red[1]), fmaxf(red[2], red[3]));
  __syncthreads();

  float se = 0.f;
  #pragma unroll
  for (int i = 0; i < 8; ++i) { v[i] = __expf(v[i] - mx); se += v[i]; }
  #pragma unroll
  for (int m = 1; m < 64; m <<= 1) se += __shfl_xor(se, m, 64);
  if ((t & 63) == 0) red[t >> 6] = se;
  __syncthreads();
  se = red[0] + red[1] + red[2] + red[3];
  __syncthreads();

  const float inv = 1.0f / se;
  float sw = 0.f;
  #pragma unroll
  for (int i = 0; i < 8; ++i) { float wi = v[i] * inv; w[t + i * 256] = wi; sw += wi; }
  #pragma unroll
  for (int m = 1; m < 64; m <<= 1) sw += __shfl_xor(sw, m, 64);
  if ((t & 63) == 0) red[t >> 6] = sw;
  __syncthreads();
  sw = red[0] + red[1] + red[2] + red[3];

  // context[b][u] = s_prev[b][u] * sum_s w[s]   (faithful to reference quirk)
  out[b * NU + t]       = sp[b * NU + t] * sw;
  out[b * NU + t + 256] = sp[b * NU + t + 256] * sw;
}

extern "C" void kernel_launch(void* const* d_in, const int* in_sizes, int n_in,
                              void* d_out, int out_size, void* d_ws, size_t ws_size,
                              hipStream_t stream) {
  (void)in_sizes; (void)n_in; (void)out_size; (void)ws_size;
  const float* s_prev = (const float*)d_in[0];
  const float* h      = (const float*)d_in[1];
  const float* Wk     = (const float*)d_in[2];
  const float* Wb     = (const float*)d_in[3];
  const float* Uk     = (const float*)d_in[4];
  const float* Ub     = (const float*)d_in[5];
  const float* Vk     = (const float*)d_in[6];
  // d_in[7] = V_bias: softmax-shift-invariant, does not affect outputs.

  float* out    = (float*)d_out;
  float* first  = (float*)d_ws;                    // 32*512 f32 = 64 KiB
  short* Wt     = (short*)((char*)d_ws + 65536);   // 512*512 bf16 = 512 KiB
  float* scores = out + NBATCH * NU;               // scores live in weights slot

  prep_w    <<<1024, 256, 0, stream>>>(Wk, Wt);
  prep_first<<<  64, 256, 0, stream>>>(s_prev, Uk, Ub, Wb, first);
  attn_main <<< 512, 512, 0, stream>>>(h, Wt, first, Vk, scores);
  softmax_ctx<<< 32, 256, 0, stream>>>(s_prev, out);
}